// Round 8
// baseline (353.764 us; speedup 1.0000x reference)
//
#include <hip/hip_runtime.h>

typedef __bf16 bf16_t;
typedef __bf16 bf16x8 __attribute__((ext_vector_type(8)));
typedef __bf16 bf16x4 __attribute__((ext_vector_type(4)));
typedef float f32x4 __attribute__((ext_vector_type(4)));

#define EMBED 2048
#define S_LEN 2048
#define BATCH 2
#define NHEADS 16
#define KVHEADS 4
#define HDIM 128
#define MROWS (BATCH * S_LEN) /* 4096 */
#define NQKV 3072
#define ATTN_SCALE 0.08838834764831845f
// scale * log2(e): QK^T then exp2 == exp(scale * qk)
#define QSCALE 0.12751744f
#define EXP_OFF2 14.426950408889634f
// log2(10000)/64
#define L2T_OVER_64 0.2076205059304601

// async global->LDS, 16B per lane, wave-uniform LDS base + lane*16
__device__ __forceinline__ void gld_lds16(const bf16_t* g, bf16_t* l) {
  __builtin_amdgcn_global_load_lds(
      (const __attribute__((address_space(1))) void*)g,
      (__attribute__((address_space(3))) void*)l, 16, 0, 0);
}

// key-permutation for the PV register-operand trick (32-block-preserving):
// A-slot (lq*8 + nt*4 + r) <-> physical key nt*16 + lq*4 + r  (within 32; bit5 kept)
__device__ __forceinline__ int perm6(int s) {
  return (s & 0x20) | ((s & 0x0C) << 1) | ((s & 0x10) >> 2) | (s & 3);
}

// ---------------- fp32 -> bf16 convert (x4 vectorized) ----------------
__global__ void k_convert(const float* __restrict__ in, bf16_t* __restrict__ out, int n4) {
  int i = blockIdx.x * blockDim.x + threadIdx.x;
  if (i >= n4) return;
  float4 v = ((const float4*)in)[i];
  bf16x4 o;
  o[0] = (bf16_t)v.x; o[1] = (bf16_t)v.y; o[2] = (bf16_t)v.z; o[3] = (bf16_t)v.w;
  ((bf16x4*)out)[i] = o;
}

// ---------------- RoPE cos/sin table: tab[s][j] = (cos, sin) ----------------
__global__ void k_tab(float2* __restrict__ tab) {
  int idx = blockIdx.x * 256 + threadIdx.x;  // 2048*64
  const int j = idx & 63, s = idx >> 6;
  const double ang = (double)s * exp2(-(double)j * L2T_OVER_64);
  tab[idx] = make_float2((float)cos(ang), (float)sin(ang));
}

// ---------------- fused QKV NT GEMM: [q|kv] = x [Wq;Wkv]^T + [bq;bkv] ----------------
// 128x128 tile, BK=64, 256 threads, DMA staging with XOR chunk swizzle.
__global__ __launch_bounds__(256, 3)
void k_gemm_qkv(const bf16_t* __restrict__ A, const bf16_t* __restrict__ B,
                const float* __restrict__ bq, const float* __restrict__ bkv,
                bf16_t* __restrict__ Cq, bf16_t* __restrict__ Ckv) {
  __shared__ __align__(16) bf16_t As[128 * 64];
  __shared__ __align__(16) bf16_t Bs[128 * 64];
  const int t = threadIdx.x;
  const int lane = t & 63;
  const int w = t >> 6;
  const int wr = (w >> 1) * 64, wc = (w & 1) * 64;
  const int l15 = lane & 15, lq = lane >> 4;
  const int m0 = blockIdx.y * 128, n0 = blockIdx.x * 128;
  const int K = EMBED;

  const f32x4 vzero = {0.f, 0.f, 0.f, 0.f};
  f32x4 acc[4][4];
#pragma unroll
  for (int mi = 0; mi < 4; ++mi)
#pragma unroll
    for (int ni = 0; ni < 4; ++ni) acc[mi][ni] = vzero;

  const int srow = w * 32 + (lane >> 3);
  const int scol = ((lane & 7) ^ (lane >> 3)) * 8;
  const bf16_t* ag = A + (size_t)(m0 + srow) * K + scol;
  const bf16_t* bg = B + (size_t)(n0 + srow) * K + scol;
  bf16_t* al = As + (w * 32) * 64;
  bf16_t* bl = Bs + (w * 32) * 64;

  for (int kt = 0; kt < K; kt += 64) {
#pragma unroll
    for (int i = 0; i < 4; ++i) {
      gld_lds16(ag + (size_t)i * 8 * K + kt, al + i * 512);
      gld_lds16(bg + (size_t)i * 8 * K + kt, bl + i * 512);
    }
    __syncthreads();
#pragma unroll
    for (int ks = 0; ks < 2; ++ks) {
      bf16x8 af[4], bfr[4];
#pragma unroll
      for (int i = 0; i < 4; ++i)
        af[i] = *(const bf16x8*)(As + (wr + i * 16 + l15) * 64 +
                                 (((ks * 4 + lq) ^ (l15 & 7)) * 8));
#pragma unroll
      for (int i = 0; i < 4; ++i)
        bfr[i] = *(const bf16x8*)(Bs + (wc + i * 16 + l15) * 64 +
                                  (((ks * 4 + lq) ^ (l15 & 7)) * 8));
#pragma unroll
      for (int mi = 0; mi < 4; ++mi)
#pragma unroll
        for (int ni = 0; ni < 4; ++ni)
          acc[mi][ni] = __builtin_amdgcn_mfma_f32_16x16x32_bf16(af[mi], bfr[ni], acc[mi][ni], 0, 0, 0);
    }
    __syncthreads();
  }

  const bool is_q = (n0 < EMBED);  // block-uniform (tile never straddles 2048)
#pragma unroll
  for (int mi = 0; mi < 4; ++mi) {
#pragma unroll
    for (int ni = 0; ni < 4; ++ni) {
      const int col = n0 + wc + ni * 16 + l15;
      const float bv = is_q ? bq[col] : bkv[col - EMBED];
#pragma unroll
      for (int r = 0; r < 4; ++r) {
        const int row = m0 + wr + mi * 16 + lq * 4 + r;
        const float v = acc[mi][ni][r] + bv;
        if (is_q)
          Cq[(size_t)row * EMBED + col] = (bf16_t)v;
        else
          Ckv[(size_t)row * 1024 + (col - EMBED)] = (bf16_t)v;
      }
    }
  }
}

// ---------------- NT GEMM (single out): C = A B^T, f32 out, swizzled staging ----------------
__global__ __launch_bounds__(256, 3)
void k_gemm_o(const bf16_t* __restrict__ A, const bf16_t* __restrict__ B,
              float* __restrict__ C, int N, int K) {
  __shared__ __align__(16) bf16_t As[128 * 64];
  __shared__ __align__(16) bf16_t Bs[128 * 64];
  const int t = threadIdx.x;
  const int lane = t & 63;
  const int w = t >> 6;
  const int wr = (w >> 1) * 64, wc = (w & 1) * 64;
  const int l15 = lane & 15, lq = lane >> 4;
  const int m0 = blockIdx.y * 128, n0 = blockIdx.x * 128;

  const f32x4 vzero = {0.f, 0.f, 0.f, 0.f};
  f32x4 acc[4][4];
#pragma unroll
  for (int mi = 0; mi < 4; ++mi)
#pragma unroll
    for (int ni = 0; ni < 4; ++ni) acc[mi][ni] = vzero;

  const int srow = w * 32 + (lane >> 3);
  const int scol = ((lane & 7) ^ (lane >> 3)) * 8;
  const bf16_t* ag = A + (size_t)(m0 + srow) * K + scol;
  const bf16_t* bg = B + (size_t)(n0 + srow) * K + scol;
  bf16_t* al = As + (w * 32) * 64;
  bf16_t* bl = Bs + (w * 32) * 64;

  for (int kt = 0; kt < K; kt += 64) {
#pragma unroll
    for (int i = 0; i < 4; ++i) {
      gld_lds16(ag + (size_t)i * 8 * K + kt, al + i * 512);
      gld_lds16(bg + (size_t)i * 8 * K + kt, bl + i * 512);
    }
    __syncthreads();
#pragma unroll
    for (int ks = 0; ks < 2; ++ks) {
      bf16x8 af[4], bfr[4];
#pragma unroll
      for (int i = 0; i < 4; ++i)
        af[i] = *(const bf16x8*)(As + (wr + i * 16 + l15) * 64 +
                                 (((ks * 4 + lq) ^ (l15 & 7)) * 8));
#pragma unroll
      for (int i = 0; i < 4; ++i)
        bfr[i] = *(const bf16x8*)(Bs + (wc + i * 16 + l15) * 64 +
                                  (((ks * 4 + lq) ^ (l15 & 7)) * 8));
#pragma unroll
      for (int mi = 0; mi < 4; ++mi)
#pragma unroll
        for (int ni = 0; ni < 4; ++ni)
          acc[mi][ni] = __builtin_amdgcn_mfma_f32_16x16x32_bf16(af[mi], bfr[ni], acc[mi][ni], 0, 0, 0);
    }
    __syncthreads();
  }

#pragma unroll
  for (int mi = 0; mi < 4; ++mi) {
#pragma unroll
    for (int ni = 0; ni < 4; ++ni) {
      const int col = n0 + wc + ni * 16 + l15;
#pragma unroll
      for (int r = 0; r < 4; ++r) {
        const int row = m0 + wr + mi * 16 + lq * 4 + r;
        C[(size_t)row * N + col] = acc[mi][ni][r];
      }
    }
  }
}

// ---------------- RoPE K (table): kv_pre bf16 [B,S,1024] cols 0..511 -> [B,KVH,S,D] ----------------
__global__ void k_rope_k(const bf16_t* __restrict__ kvp, const float2* __restrict__ tab,
                         bf16_t* __restrict__ ko) {
  int idx = blockIdx.x * 256 + threadIdx.x;  // B*S*KVH*64
  const int j = idx & 63; idx >>= 6;
  const int kh = idx & 3; idx >>= 2;
  const int s = idx & 2047;
  const int b = idx >> 11;
  const float2 cs = tab[s * 64 + j];
  const bf16_t* src = kvp + ((size_t)(b * S_LEN + s)) * 1024 + kh * HDIM;
  const float t1 = (float)src[j], t2 = (float)src[j + 64];
  bf16_t* dst = ko + ((size_t)((b * KVHEADS + kh) * S_LEN + s)) * HDIM;
  dst[j]      = (bf16_t)(t1 * cs.x - t2 * cs.y);
  dst[j + 64] = (bf16_t)(t2 * cs.x + t1 * cs.y);
}

// ---------------- V pack: kv_pre bf16 cols 512..1023 -> VT bf16 [B,KVH,D,S], perm6 keys ----------------
__global__ void k_pack_v(const bf16_t* __restrict__ kvp, bf16_t* __restrict__ vt) {
  int idx = blockIdx.x * 256 + threadIdx.x;  // B*S*KVH*128
  const int d = idx & 127; idx >>= 7;
  const int kh = idx & 3; idx >>= 2;
  const int s = idx & 2047;
  const int b = idx >> 11;
  const bf16_t v = kvp[((size_t)(b * S_LEN + s)) * 1024 + 512 + kh * HDIM + d];
  const int sp = (s & ~63) | perm6(s & 63);
  vt[((size_t)((b * KVHEADS + kh) * HDIM + d)) * S_LEN + sp] = v;
}

// ---------------- Flash attention, double-buffered 32-key tiles ---------------------------
// grid: (S/64, B*H), 128 threads (2 waves). Wave w owns q-rows [w*32, w*32+32) as 2 sets.
// In-kernel Q-RoPE (exp2-domain scale); DMA-staged K/V ping-pong; register-P PV; in-place O.
__global__ __launch_bounds__(128, 2)
void k_attn(bf16_t* __restrict__ QO, const bf16_t* __restrict__ Kc,
            const bf16_t* __restrict__ VT, const float2* __restrict__ tab) {
  // Ks[buf]: 32 keys x 128 d, 256B rows, chunk c at slot c^(r&15)
  // Vs[buf]: paired-d rows: row r holds d=2r (chunks 0..3) and d=2r+1 (chunks 4..7),
  //          32 perm-keys, 128B rows, chunk c at slot c^(r&7)
  __shared__ __align__(16) bf16_t Ks[2][32 * 128];
  __shared__ __align__(16) bf16_t Vs[2][64 * 64];
  const int t = threadIdx.x, lane = t & 63, w = t >> 6;
  const int l15 = lane & 15, lq = lane >> 4;
  const int bh = blockIdx.y, b = bh >> 4, h = bh & 15, kvh = h >> 2;
  const int s0 = blockIdx.x * 64;

  const bf16_t* Kh = Kc + (size_t)(b * KVHEADS + kvh) * S_LEN * HDIM;
  const bf16_t* Vh = VT + (size_t)(b * KVHEADS + kvh) * HDIM * S_LEN;

  // staging offsets (kt-invariant, per-lane)
  int koff[4];
#pragma unroll
  for (int j = 0; j < 4; ++j) {
    const int r = w * 16 + j * 4 + (lane >> 4);  // key row 0..31
    koff[j] = r * HDIM + (((lane & 15) ^ (r & 15)) * 8);
  }
  int voff[4];
#pragma unroll
  for (int j = 0; j < 4; ++j) {
    const int r = w * 32 + j * 8 + (lane >> 3);     // LDS row 0..63
    const int cp = (lane & 7) ^ (r & 7);            // unswizzled chunk
    const int d = 2 * r + (cp >> 2);
    voff[j] = d * S_LEN + (cp & 3) * 8;
  }
  bf16_t* kd[2] = {Ks[0] + (w * 16) * 128, Ks[1] + (w * 16) * 128};
  bf16_t* vd[2] = {Vs[0] + (w * 32) * 64, Vs[1] + (w * 32) * 64};

  auto stage = [&](int buf, int kt) {
    const bf16_t* kb = Kh + (size_t)kt * HDIM;
    const bf16_t* vb = Vh + kt;
#pragma unroll
    for (int j = 0; j < 4; ++j) {
      gld_lds16(kb + koff[j], kd[buf] + j * 512);
      gld_lds16(vb + voff[j], vd[buf] + j * 512);
    }
  };

  // Q fragments (B operand): load pre-RoPE rows, rotate via table, fold exp2-domain scale.
  bf16x8 qf[2][4];
#pragma unroll
  for (int p = 0; p < 2; ++p) {
    const int s = s0 + w * 32 + p * 16 + l15;
    const bf16_t* qrow = QO + ((size_t)(b * S_LEN + s)) * EMBED + h * HDIM;
#pragma unroll
    for (int kh2 = 0; kh2 < 2; ++kh2) {
      const int d0 = kh2 * 32 + lq * 8;  // in [0,64)
      const bf16x8 lo = *(const bf16x8*)(qrow + d0);
      const bf16x8 hi = *(const bf16x8*)(qrow + d0 + 64);
      const float2* tp = tab + s * 64 + d0;
#pragma unroll
      for (int j = 0; j < 8; ++j) {
        const float c = tp[j].x, sn = tp[j].y;
        const float t1 = (float)lo[j], t2 = (float)hi[j];
        qf[p][kh2][j]     = (bf16_t)((t1 * c - t2 * sn) * QSCALE);
        qf[p][kh2 + 2][j] = (bf16_t)((t2 * c + t1 * sn) * QSCALE);
      }
    }
  }

  const f32x4 vzero = {0.f, 0.f, 0.f, 0.f};
  f32x4 oacc[2][8];
#pragma unroll
  for (int p = 0; p < 2; ++p)
#pragma unroll
    for (int dt = 0; dt < 8; ++dt) oacc[p][dt] = vzero;
  float l_part[2] = {0.f, 0.f};

  stage(0, 0);

  for (int it = 0; it < S_LEN / 32; ++it) {
    const int buf = it & 1;
    __syncthreads();  // vmcnt(0) drain: waits DMA for `buf` (issued one compute-phase ago)
    if (it + 1 < S_LEN / 32) stage(buf ^ 1, (it + 1) * 32);

    const bf16_t* ksb = Ks[buf];
    const bf16_t* vsb = Vs[buf];

    // S^T = K Q^T over 32 keys; exp2 immediately; P packed straight into A-frags
    bf16x8 pf0, pf1;
#pragma unroll
    for (int nt = 0; nt < 2; ++nt) {
      f32x4 a0 = vzero, a1 = vzero;
#pragma unroll
      for (int ks = 0; ks < 4; ++ks) {
        bf16x8 kf = *(const bf16x8*)(ksb + (nt * 16 + l15) * 128 +
                                     (((ks * 4 + lq) ^ l15) * 8));
        a0 = __builtin_amdgcn_mfma_f32_16x16x32_bf16(kf, qf[0][ks], a0, 0, 0, 0);
        a1 = __builtin_amdgcn_mfma_f32_16x16x32_bf16(kf, qf[1][ks], a1, 0, 0, 0);
      }
#pragma unroll
      for (int r = 0; r < 4; ++r) {
        const float p0 = exp2f(a0[r] - EXP_OFF2);
        const float p1 = exp2f(a1[r] - EXP_OFF2);
        l_part[0] += p0;
        l_part[1] += p1;
        pf0[nt * 4 + r] = (bf16_t)p0;
        pf1[nt * 4 + r] = (bf16_t)p1;
      }
    }

    // O += P V (single K=32 MFMA per dt per set)
#pragma unroll
    for (int dt = 0; dt < 8; ++dt) {
      const int row = dt * 8 + (l15 >> 1);
      const int slot = ((l15 & 1) * 4 + lq) ^ (l15 >> 1);
      bf16x8 vf = *(const bf16x8*)(vsb + row * 64 + slot * 8);
      oacc[0][dt] = __builtin_amdgcn_mfma_f32_16x16x32_bf16(pf0, vf, oacc[0][dt], 0, 0, 0);
      oacc[1][dt] = __builtin_amdgcn_mfma_f32_16x16x32_bf16(pf1, vf, oacc[1][dt], 0, 0, 0);
    }
  }

  // epilogue: normalize, write O in place of this block's Q tile (same rows, same cols)
#pragma unroll
  for (int p = 0; p < 2; ++p) {
    float lp = l_part[p];
    lp += __shfl_xor(lp, 16, 64);
    lp += __shfl_xor(lp, 32, 64);
#pragma unroll
    for (int r = 0; r < 4; ++r) {
      const float inv = 1.0f / __shfl(lp, lq * 4 + r, 64);
      const int s = s0 + w * 32 + p * 16 + lq * 4 + r;
      bf16_t* dst = QO + ((size_t)(b * S_LEN + s)) * EMBED + h * HDIM;
#pragma unroll
      for (int dt = 0; dt < 8; ++dt) dst[dt * 16 + l15] = (bf16_t)(oacc[p][dt][r] * inv);
    }
  }
}

// ---------------- launch ----------------
extern "C" void kernel_launch(void* const* d_in, const int* in_sizes, int n_in,
                              void* d_out, int out_size, void* d_ws, size_t ws_size,
                              hipStream_t stream) {
  const float* x   = (const float*)d_in[0];
  const float* Wq  = (const float*)d_in[1];
  const float* bq  = (const float*)d_in[2];
  const float* Wkv = (const float*)d_in[3];
  const float* bkv = (const float*)d_in[4];
  const float* Wo  = (const float*)d_in[5];
  float* out = (float*)d_out;

  // Buffer schedule (ws 24MB, d_out 32MB; every region dead before overwrite):
  //  outb phase1: [0:12) wqkv_bf | [12:28) x_bf
  //  outb phase2: [0:4) k_bf | [4:8) vt_bf | [8:9) tab
  //  ws: [0:16) q_pre (in-place -> o_bf) | [16:24) kv_pre -> wo_bf
  //  final GEMM reads only ws, writes all of d_out.
  char* ws = (char*)d_ws;
  char* outb = (char*)d_out;
  const size_t MB = 1024 * 1024;
  bf16_t* wqkv_bf = (bf16_t*)(outb);            // [3072,2048] bf16 (Wq rows then Wkv rows)
  bf16_t* x_bf    = (bf16_t*)(outb + 12 * MB);  // [4096,2048] bf16
  bf16_t* q_pre   = (bf16_t*)(ws);              // [4096,2048] bf16, becomes o in place
  bf16_t* kv_pre  = (bf16_t*)(ws + 16 * MB);    // [4096,1024] bf16
  bf16_t* k_bf    = (bf16_t*)(outb);
  bf16_t* vt_bf   = (bf16_t*)(outb + 4 * MB);
  float2* tab     = (float2*)(outb + 8 * MB);
  bf16_t* wo_bf   = (bf16_t*)(ws + 16 * MB);    // reuses kv_pre slot after rope/pack
  (void)ws_size;

  // phase 1: converts (Wq and Wkv stacked into one [3072,2048] weight)
  k_convert<<<(EMBED * EMBED / 4) / 256, 256, 0, stream>>>(Wq, wqkv_bf, EMBED * EMBED / 4);
  k_convert<<<(1024 * EMBED / 4) / 256, 256, 0, stream>>>(
      Wkv, wqkv_bf + (size_t)EMBED * EMBED, 1024 * EMBED / 4);
  k_convert<<<(MROWS * EMBED / 4) / 256, 256, 0, stream>>>(x, x_bf, MROWS * EMBED / 4);

  // fused QKV projection
  k_gemm_qkv<<<dim3(NQKV / 128, MROWS / 128), 256, 0, stream>>>(
      x_bf, wqkv_bf, bq, bkv, q_pre, kv_pre);

  // phase 2: RoPE table, K/V layout (phase-1 outb regions now dead)
  k_tab<<<(S_LEN * 64) / 256, 256, 0, stream>>>(tab);
  k_rope_k<<<(BATCH * S_LEN * KVHEADS * 64) / 256, 256, 0, stream>>>(kv_pre, tab, k_bf);
  k_pack_v<<<(BATCH * S_LEN * KVHEADS * 128) / 256, 256, 0, stream>>>(kv_pre, vt_bf);

  // Wo convert into the now-dead kv_pre slot
  k_convert<<<(EMBED * EMBED / 4) / 256, 256, 0, stream>>>(Wo, wo_bf, EMBED * EMBED / 4);

  // attention: reads q_pre (RoPE in-kernel), writes normalized O in place
  k_attn<<<dim3(S_LEN / 64, BATCH * NHEADS), 128, 0, stream>>>(q_pre, k_bf, vt_bf, tab);

  // out = o Wo^T (f32, overwrites all of d_out; inputs live only in ws)
  k_gemm_o<<<dim3(EMBED / 128, MROWS / 128), 256, 0, stream>>>(
      q_pre, wo_bf, out, EMBED, EMBED);
}

// Round 9
// 316.581 us; speedup vs baseline: 1.1175x; 1.1175x over previous
//
#include <hip/hip_runtime.h>

typedef __bf16 bf16_t;
typedef __bf16 bf16x8 __attribute__((ext_vector_type(8)));
typedef __bf16 bf16x4 __attribute__((ext_vector_type(4)));
typedef float f32x4 __attribute__((ext_vector_type(4)));

#define EMBED 2048
#define S_LEN 2048
#define BATCH 2
#define NHEADS 16
#define KVHEADS 4
#define HDIM 128
#define MROWS (BATCH * S_LEN) /* 4096 */
#define NQKV 3072
#define ATTN_SCALE 0.08838834764831845f
// log2(10000)/64
#define L2T_OVER_64 0.2076205059304601
#define EXP_OFF 10.0f

// async global->LDS, 16B per lane, wave-uniform LDS base + lane*16
__device__ __forceinline__ void gld_lds16(const bf16_t* g, bf16_t* l) {
  __builtin_amdgcn_global_load_lds(
      (const __attribute__((address_space(1))) void*)g,
      (__attribute__((address_space(3))) void*)l, 16, 0, 0);
}

// key-permutation for the PV register-operand trick:
// MFMA A/B slot (k2,quad,a,r) <-> physical key k2*32 + a*16 + quad*4 + r.
__device__ __forceinline__ int perm6(int s) {
  return (s & 0x20) | ((s & 0x0C) << 1) | ((s & 0x10) >> 2) | (s & 3);
}

// ---------------- fused fp32 -> bf16 convert of Wq|Wkv|x into contiguous dest ----------------
#define N4_WQ (EMBED * EMBED / 4)
#define N4_WKV (1024 * EMBED / 4)
#define N4_X (MROWS * EMBED / 4)
__global__ void k_convert3(const float* __restrict__ wq, const float* __restrict__ wkv,
                           const float* __restrict__ x, bf16_t* __restrict__ out) {
  const int i = blockIdx.x * blockDim.x + threadIdx.x;  // [0, N4_WQ+N4_WKV+N4_X)
  const float4* src;
  int j = i;
  if (i < N4_WQ) {
    src = (const float4*)wq;
  } else if (i < N4_WQ + N4_WKV) {
    src = (const float4*)wkv; j = i - N4_WQ;
  } else {
    src = (const float4*)x; j = i - (N4_WQ + N4_WKV);
  }
  const float4 v = src[j];
  bf16x4 o;
  o[0] = (bf16_t)v.x; o[1] = (bf16_t)v.y; o[2] = (bf16_t)v.z; o[3] = (bf16_t)v.w;
  ((bf16x4*)out)[i] = o;
}

// ---------------- single fp32 -> bf16 convert (x4 vectorized) ----------------
__global__ void k_convert(const float* __restrict__ in, bf16_t* __restrict__ out, int n4) {
  int i = blockIdx.x * blockDim.x + threadIdx.x;
  if (i >= n4) return;
  float4 v = ((const float4*)in)[i];
  bf16x4 o;
  o[0] = (bf16_t)v.x; o[1] = (bf16_t)v.y; o[2] = (bf16_t)v.z; o[3] = (bf16_t)v.w;
  ((bf16x4*)out)[i] = o;
}

// ---------------- RoPE cos/sin table: tab[s][j] = (cos, sin) ----------------
__global__ void k_tab(float2* __restrict__ tab) {
  int idx = blockIdx.x * 256 + threadIdx.x;  // 2048*64
  const int j = idx & 63, s = idx >> 6;
  const double ang = (double)s * exp2(-(double)j * L2T_OVER_64);
  tab[idx] = make_float2((float)cos(ang), (float)sin(ang));
}

// ---------------- fused QKV NT GEMM: [q|kv] = x [Wq;Wkv]^T + [bq;bkv] ----------------
// 128x128 tile, BK=64, 256 threads, DMA staging with XOR chunk swizzle.
__global__ __launch_bounds__(256, 3)
void k_gemm_qkv(const bf16_t* __restrict__ A, const bf16_t* __restrict__ B,
                const float* __restrict__ bq, const float* __restrict__ bkv,
                bf16_t* __restrict__ Cq, bf16_t* __restrict__ Ckv) {
  __shared__ __align__(16) bf16_t As[128 * 64];
  __shared__ __align__(16) bf16_t Bs[128 * 64];
  const int t = threadIdx.x;
  const int lane = t & 63;
  const int w = t >> 6;
  const int wr = (w >> 1) * 64, wc = (w & 1) * 64;
  const int l15 = lane & 15, lq = lane >> 4;
  const int m0 = blockIdx.y * 128, n0 = blockIdx.x * 128;
  const int K = EMBED;

  const f32x4 vzero = {0.f, 0.f, 0.f, 0.f};
  f32x4 acc[4][4];
#pragma unroll
  for (int mi = 0; mi < 4; ++mi)
#pragma unroll
    for (int ni = 0; ni < 4; ++ni) acc[mi][ni] = vzero;

  const int srow = w * 32 + (lane >> 3);
  const int scol = ((lane & 7) ^ (lane >> 3)) * 8;
  const bf16_t* ag = A + (size_t)(m0 + srow) * K + scol;
  const bf16_t* bg = B + (size_t)(n0 + srow) * K + scol;
  bf16_t* al = As + (w * 32) * 64;
  bf16_t* bl = Bs + (w * 32) * 64;

  for (int kt = 0; kt < K; kt += 64) {
#pragma unroll
    for (int i = 0; i < 4; ++i) {
      gld_lds16(ag + (size_t)i * 8 * K + kt, al + i * 512);
      gld_lds16(bg + (size_t)i * 8 * K + kt, bl + i * 512);
    }
    __syncthreads();
#pragma unroll
    for (int ks = 0; ks < 2; ++ks) {
      bf16x8 af[4], bfr[4];
#pragma unroll
      for (int i = 0; i < 4; ++i)
        af[i] = *(const bf16x8*)(As + (wr + i * 16 + l15) * 64 +
                                 (((ks * 4 + lq) ^ (l15 & 7)) * 8));
#pragma unroll
      for (int i = 0; i < 4; ++i)
        bfr[i] = *(const bf16x8*)(Bs + (wc + i * 16 + l15) * 64 +
                                  (((ks * 4 + lq) ^ (l15 & 7)) * 8));
#pragma unroll
      for (int mi = 0; mi < 4; ++mi)
#pragma unroll
        for (int ni = 0; ni < 4; ++ni)
          acc[mi][ni] = __builtin_amdgcn_mfma_f32_16x16x32_bf16(af[mi], bfr[ni], acc[mi][ni], 0, 0, 0);
    }
    __syncthreads();
  }

  const bool is_q = (n0 < EMBED);  // block-uniform (tile never straddles 2048)
#pragma unroll
  for (int mi = 0; mi < 4; ++mi) {
#pragma unroll
    for (int ni = 0; ni < 4; ++ni) {
      const int col = n0 + wc + ni * 16 + l15;
      const float bv = is_q ? bq[col] : bkv[col - EMBED];
#pragma unroll
      for (int r = 0; r < 4; ++r) {
        const int row = m0 + wr + mi * 16 + lq * 4 + r;
        const float v = acc[mi][ni][r] + bv;
        if (is_q)
          Cq[(size_t)row * EMBED + col] = (bf16_t)v;
        else
          Ckv[(size_t)row * 1024 + (col - EMBED)] = (bf16_t)v;
      }
    }
  }
}

// ---------------- NT GEMM (single out): C = A B^T, f32 out, swizzled staging ----------------
__global__ __launch_bounds__(256, 3)
void k_gemm_o(const bf16_t* __restrict__ A, const bf16_t* __restrict__ B,
              float* __restrict__ C, int N, int K) {
  __shared__ __align__(16) bf16_t As[128 * 64];
  __shared__ __align__(16) bf16_t Bs[128 * 64];
  const int t = threadIdx.x;
  const int lane = t & 63;
  const int w = t >> 6;
  const int wr = (w >> 1) * 64, wc = (w & 1) * 64;
  const int l15 = lane & 15, lq = lane >> 4;
  const int m0 = blockIdx.y * 128, n0 = blockIdx.x * 128;

  const f32x4 vzero = {0.f, 0.f, 0.f, 0.f};
  f32x4 acc[4][4];
#pragma unroll
  for (int mi = 0; mi < 4; ++mi)
#pragma unroll
    for (int ni = 0; ni < 4; ++ni) acc[mi][ni] = vzero;

  const int srow = w * 32 + (lane >> 3);
  const int scol = ((lane & 7) ^ (lane >> 3)) * 8;
  const bf16_t* ag = A + (size_t)(m0 + srow) * K + scol;
  const bf16_t* bg = B + (size_t)(n0 + srow) * K + scol;
  bf16_t* al = As + (w * 32) * 64;
  bf16_t* bl = Bs + (w * 32) * 64;

  for (int kt = 0; kt < K; kt += 64) {
#pragma unroll
    for (int i = 0; i < 4; ++i) {
      gld_lds16(ag + (size_t)i * 8 * K + kt, al + i * 512);
      gld_lds16(bg + (size_t)i * 8 * K + kt, bl + i * 512);
    }
    __syncthreads();
#pragma unroll
    for (int ks = 0; ks < 2; ++ks) {
      bf16x8 af[4], bfr[4];
#pragma unroll
      for (int i = 0; i < 4; ++i)
        af[i] = *(const bf16x8*)(As + (wr + i * 16 + l15) * 64 +
                                 (((ks * 4 + lq) ^ (l15 & 7)) * 8));
#pragma unroll
      for (int i = 0; i < 4; ++i)
        bfr[i] = *(const bf16x8*)(Bs + (wc + i * 16 + l15) * 64 +
                                  (((ks * 4 + lq) ^ (l15 & 7)) * 8));
#pragma unroll
      for (int mi = 0; mi < 4; ++mi)
#pragma unroll
        for (int ni = 0; ni < 4; ++ni)
          acc[mi][ni] = __builtin_amdgcn_mfma_f32_16x16x32_bf16(af[mi], bfr[ni], acc[mi][ni], 0, 0, 0);
    }
    __syncthreads();
  }

#pragma unroll
  for (int mi = 0; mi < 4; ++mi) {
#pragma unroll
    for (int ni = 0; ni < 4; ++ni) {
      const int col = n0 + wc + ni * 16 + l15;
#pragma unroll
      for (int r = 0; r < 4; ++r) {
        const int row = m0 + wr + mi * 16 + lq * 4 + r;
        C[(size_t)row * N + col] = acc[mi][ni][r];
      }
    }
  }
}

// ---------------- fused RoPE-K + V-pack ----------------
// one thread per (b,s,kh,j), j in [0,64): K rope (2 elems) + V pack d=j and d=j+64.
__global__ void k_rope_pack(const bf16_t* __restrict__ kvp, const float2* __restrict__ tab,
                            bf16_t* __restrict__ ko, bf16_t* __restrict__ vt) {
  int idx = blockIdx.x * 256 + threadIdx.x;  // B*S*KVH*64
  const int j = idx & 63; idx >>= 6;
  const int kh = idx & 3; idx >>= 2;
  const int s = idx & 2047;
  const int b = idx >> 11;
  const bf16_t* src = kvp + ((size_t)(b * S_LEN + s)) * 1024 + kh * HDIM;

  // K rope
  const float2 cs = tab[s * 64 + j];
  const float t1 = (float)src[j], t2 = (float)src[j + 64];
  bf16_t* kdst = ko + ((size_t)((b * KVHEADS + kh) * S_LEN + s)) * HDIM;
  kdst[j]      = (bf16_t)(t1 * cs.x - t2 * cs.y);
  kdst[j + 64] = (bf16_t)(t2 * cs.x + t1 * cs.y);

  // V pack (perm6 key within 64-block)
  const int sp = (s & ~63) | perm6(s & 63);
  bf16_t* vbase = vt + ((size_t)(b * KVHEADS + kh) * HDIM) * S_LEN + sp;
  vbase[(size_t)j * S_LEN]        = src[512 + j];
  vbase[(size_t)(j + 64) * S_LEN] = src[512 + j + 64];
}

// ---------------- Flash attention (round-7 proven version) -------------------------------
// grid: (S/64, B*H), 128 threads (2 waves). Wave w owns q-rows [w*32, w*32+32) as 2 sets.
// In-kernel Q-RoPE; DMA-staged K/V with XOR chunk swizzle; register-P PV; in-place O.
__global__ __launch_bounds__(128, 2)
void k_attn(bf16_t* __restrict__ QO, const bf16_t* __restrict__ Kc,
            const bf16_t* __restrict__ VT, const float2* __restrict__ tab) {
  __shared__ __align__(16) bf16_t Ks[64 * 128];   // [key][d], 16 chunks/row, slot c^(r&15)
  __shared__ __align__(16) bf16_t Vs[128 * 64];   // [d][perm-key], 8 chunks/row, slot c^(r&7)
  const int t = threadIdx.x, lane = t & 63, w = t >> 6;
  const int l15 = lane & 15, lq = lane >> 4;
  const int bh = blockIdx.y, b = bh >> 4, h = bh & 15, kvh = h >> 2;
  const int s0 = blockIdx.x * 64;

  const bf16_t* Kh = Kc + (size_t)(b * KVHEADS + kvh) * S_LEN * HDIM;
  const bf16_t* Vh = VT + (size_t)(b * KVHEADS + kvh) * HDIM * S_LEN;

  // Q fragments (B operand): load pre-RoPE rows, rotate via table, fold scale.
  bf16x8 qf[2][4];
#pragma unroll
  for (int p = 0; p < 2; ++p) {
    const int s = s0 + w * 32 + p * 16 + l15;
    const bf16_t* qrow = QO + ((size_t)(b * S_LEN + s)) * EMBED + h * HDIM;
#pragma unroll
    for (int kh2 = 0; kh2 < 2; ++kh2) {
      const int d0 = kh2 * 32 + lq * 8;  // in [0,64)
      const bf16x8 lo = *(const bf16x8*)(qrow + d0);
      const bf16x8 hi = *(const bf16x8*)(qrow + d0 + 64);
      const float2* tp = tab + s * 64 + d0;
#pragma unroll
      for (int j = 0; j < 8; ++j) {
        const float c = tp[j].x, sn = tp[j].y;
        const float t1 = (float)lo[j], t2 = (float)hi[j];
        qf[p][kh2][j]     = (bf16_t)((t1 * c - t2 * sn) * ATTN_SCALE);
        qf[p][kh2 + 2][j] = (bf16_t)((t2 * c + t1 * sn) * ATTN_SCALE);
      }
    }
  }

  const f32x4 vzero = {0.f, 0.f, 0.f, 0.f};
  f32x4 oacc[2][8];
#pragma unroll
  for (int p = 0; p < 2; ++p)
#pragma unroll
    for (int dt = 0; dt < 8; ++dt) oacc[p][dt] = vzero;
  float l_part[2] = {0.f, 0.f};

  // K staging: instr j covers rows w*32+j*4+(lane>>4); r&15 = (j&3)*4 | (lane>>4).
  int koff[8];
#pragma unroll
  for (int j = 0; j < 8; ++j) {
    const int r15 = ((j & 3) * 4) | (lane >> 4);
    koff[j] = (w * 32 + j * 4 + (lane >> 4)) * HDIM + (((lane & 15) ^ r15) * 8);
  }
  // V staging: instr j covers rows w*64+j*8+(lane>>3); r&7 = lane>>3.
  const bf16_t* vsrc = Vh + (size_t)(w * 64 + (lane >> 3)) * S_LEN +
                       (((lane & 7) ^ (lane >> 3)) * 8);
  bf16_t* kdst = Ks + (w * 32) * HDIM;
  bf16_t* vdst = Vs + (w * 64) * 64;

  for (int kt = 0; kt < S_LEN; kt += 64) {
    const bf16_t* kbase = Kh + (size_t)kt * HDIM;
#pragma unroll
    for (int j = 0; j < 8; ++j) {
      gld_lds16(kbase + koff[j], kdst + j * 512);
      gld_lds16(vsrc + kt + (size_t)j * 8 * S_LEN, vdst + j * 512);
    }
    __syncthreads();

    // S^T = K Q^T, exp applied immediately; P packed straight into A-frags
    bf16x8 pf[2][2];
#pragma unroll
    for (int nt = 0; nt < 4; ++nt) {
      f32x4 a0 = vzero, a1 = vzero;
#pragma unroll
      for (int ks = 0; ks < 4; ++ks) {
        bf16x8 kf = *(const bf16x8*)(Ks + (nt * 16 + l15) * 128 +
                                     (((ks * 4 + lq) ^ l15) * 8));
        a0 = __builtin_amdgcn_mfma_f32_16x16x32_bf16(kf, qf[0][ks], a0, 0, 0, 0);
        a1 = __builtin_amdgcn_mfma_f32_16x16x32_bf16(kf, qf[1][ks], a1, 0, 0, 0);
      }
      const int k2 = nt >> 1, aa = nt & 1;
#pragma unroll
      for (int r = 0; r < 4; ++r) {
        const float p0 = __expf(a0[r] - EXP_OFF);
        const float p1 = __expf(a1[r] - EXP_OFF);
        l_part[0] += p0;
        l_part[1] += p1;
        pf[0][k2][aa * 4 + r] = (bf16_t)p0;
        pf[1][k2][aa * 4 + r] = (bf16_t)p1;
      }
    }

    // O += P V : each V-frag read feeds both q-sets
#pragma unroll
    for (int dt = 0; dt < 8; ++dt) {
#pragma unroll
      for (int k2 = 0; k2 < 2; ++k2) {
        bf16x8 vf = *(const bf16x8*)(Vs + (dt * 16 + l15) * 64 +
                                     (((k2 * 4 + lq) ^ (l15 & 7)) * 8));
        oacc[0][dt] = __builtin_amdgcn_mfma_f32_16x16x32_bf16(pf[0][k2], vf, oacc[0][dt], 0, 0, 0);
        oacc[1][dt] = __builtin_amdgcn_mfma_f32_16x16x32_bf16(pf[1][k2], vf, oacc[1][dt], 0, 0, 0);
      }
    }
    __syncthreads();
  }

  // epilogue: normalize, write O in place of this block's Q tile (same rows, same cols)
#pragma unroll
  for (int p = 0; p < 2; ++p) {
    float lp = l_part[p];
    lp += __shfl_xor(lp, 16, 64);
    lp += __shfl_xor(lp, 32, 64);
#pragma unroll
    for (int r = 0; r < 4; ++r) {
      const float inv = 1.0f / __shfl(lp, lq * 4 + r, 64);
      const int s = s0 + w * 32 + p * 16 + lq * 4 + r;
      bf16_t* dst = QO + ((size_t)(b * S_LEN + s)) * EMBED + h * HDIM;
#pragma unroll
      for (int dt = 0; dt < 8; ++dt) dst[dt * 16 + l15] = (bf16_t)(oacc[p][dt][r] * inv);
    }
  }
}

// ---------------- launch ----------------
extern "C" void kernel_launch(void* const* d_in, const int* in_sizes, int n_in,
                              void* d_out, int out_size, void* d_ws, size_t ws_size,
                              hipStream_t stream) {
  const float* x   = (const float*)d_in[0];
  const float* Wq  = (const float*)d_in[1];
  const float* bq  = (const float*)d_in[2];
  const float* Wkv = (const float*)d_in[3];
  const float* bkv = (const float*)d_in[4];
  const float* Wo  = (const float*)d_in[5];
  float* out = (float*)d_out;

  // Buffer schedule (ws 24MB, d_out 32MB; every region dead before overwrite):
  //  outb phase1: [0:12) wqkv_bf | [12:28) x_bf
  //  outb phase2: [0:4) k_bf | [4:8) vt_bf | [8:9) tab
  //  ws: [0:16) q_pre (in-place -> o_bf) | [16:24) kv_pre -> wo_bf
  //  final GEMM reads only ws, writes all of d_out.
  char* ws = (char*)d_ws;
  char* outb = (char*)d_out;
  const size_t MB = 1024 * 1024;
  bf16_t* wqkv_bf = (bf16_t*)(outb);            // [3072,2048] bf16 (Wq rows then Wkv rows)
  bf16_t* x_bf    = (bf16_t*)(outb + 12 * MB);  // [4096,2048] bf16
  bf16_t* q_pre   = (bf16_t*)(ws);              // [4096,2048] bf16, becomes o in place
  bf16_t* kv_pre  = (bf16_t*)(ws + 16 * MB);    // [4096,1024] bf16
  bf16_t* k_bf    = (bf16_t*)(outb);
  bf16_t* vt_bf   = (bf16_t*)(outb + 4 * MB);
  float2* tab     = (float2*)(outb + 8 * MB);
  bf16_t* wo_bf   = (bf16_t*)(ws + 16 * MB);    // reuses kv_pre slot after rope/pack
  (void)ws_size;

  // phase 1: one fused convert (Wq|Wkv|x -> contiguous [0:28MB) of outb)
  k_convert3<<<(N4_WQ + N4_WKV + N4_X) / 256, 256, 0, stream>>>(Wq, Wkv, x, wqkv_bf);

  // fused QKV projection
  k_gemm_qkv<<<dim3(NQKV / 128, MROWS / 128), 256, 0, stream>>>(
      x_bf, wqkv_bf, bq, bkv, q_pre, kv_pre);

  // phase 2: RoPE table, fused K-rope + V-pack (phase-1 outb regions now dead)
  k_tab<<<(S_LEN * 64) / 256, 256, 0, stream>>>(tab);
  k_rope_pack<<<(BATCH * S_LEN * KVHEADS * 64) / 256, 256, 0, stream>>>(
      kv_pre, tab, k_bf, vt_bf);

  // Wo convert into the now-dead kv_pre slot
  k_convert<<<(EMBED * EMBED / 4) / 256, 256, 0, stream>>>(Wo, wo_bf, EMBED * EMBED / 4);

  // attention: reads q_pre (RoPE in-kernel), writes normalized O in place
  k_attn<<<dim3(S_LEN / 64, BATCH * NHEADS), 128, 0, stream>>>(q_pre, k_bf, vt_bf, tab);

  // out = o Wo^T (f32, overwrites all of d_out; inputs live only in ws)
  k_gemm_o<<<dim3(EMBED / 128, MROWS / 128), 256, 0, stream>>>(
      q_pre, wo_bf, out, EMBED, EMBED);
}